// Round 1
// baseline (845.513 us; speedup 1.0000x reference)
//
#include <hip/hip_runtime.h>
#include <math.h>

#define MIN_NORM  1e-7f
#define BALL_EPS  4e-3f
#define ATANH_EPS 1e-7f

// One row (D=64 fp32) per 16 lanes; each lane owns one float4 (16 B).
// Wave = 64 lanes = 4 rows. Reductions are segmented shfl_xor at width 16.
__global__ __launch_bounds__(256) void
act_hyp_kernel(const float* __restrict__ x, const float* __restrict__ c,
               float* __restrict__ out, int nrows) {
    const int tid  = blockIdx.x * blockDim.x + threadIdx.x;
    const int row  = tid >> 4;          // 16 lanes per row
    if (row >= nrows) return;

    const float sqrt_c = sqrtf(c[0]);   // uniform; compiler scalarizes

    // coalesced: float4 index == tid (byte offset = tid*16, contiguous)
    float4 v = ((const float4*)x)[tid];

    // ---- ||x|| ----
    float ss = v.x*v.x + v.y*v.y + v.z*v.z + v.w*v.w;
    #pragma unroll
    for (int off = 8; off >= 1; off >>= 1)
        ss += __shfl_xor(ss, off, 16);
    const float xn   = fmaxf(sqrtf(ss), MIN_NORM);
    const float scxn = sqrt_c * xn;
    const float arg  = fminf(scxn, 1.0f - ATANH_EPS);
    const float s1   = atanhf(arg) / scxn;      // logmap0 scale

    // ---- u = relu(x * s1) ----
    float4 u;
    u.x = fmaxf(v.x * s1, 0.0f);
    u.y = fmaxf(v.y * s1, 0.0f);
    u.z = fmaxf(v.z * s1, 0.0f);
    u.w = fmaxf(v.w * s1, 0.0f);

    // ---- ||u|| ----
    float us = u.x*u.x + u.y*u.y + u.z*u.z + u.w*u.w;
    #pragma unroll
    for (int off = 8; off >= 1; off >>= 1)
        us += __shfl_xor(us, off, 16);
    const float un   = fmaxf(sqrtf(us), MIN_NORM);
    const float scun = sqrt_c * un;
    const float s2   = tanhf(scun) / scun;      // expmap0 scale

    // ---- proj: ||y|| = un * s2 (y is uniform scaling of u) ----
    const float yn      = fmaxf(un * s2, MIN_NORM);
    const float maxnorm = (1.0f - BALL_EPS) / sqrt_c;
    const float s3      = (yn > maxnorm) ? (maxnorm / yn) : 1.0f;
    const float s       = s2 * s3;

    float4 o;
    o.x = u.x * s; o.y = u.y * s; o.z = u.z * s; o.w = u.w * s;
    ((float4*)out)[tid] = o;
}

extern "C" void kernel_launch(void* const* d_in, const int* in_sizes, int n_in,
                              void* d_out, int out_size, void* d_ws, size_t ws_size,
                              hipStream_t stream) {
    const float* x = (const float*)d_in[0];
    const float* c = (const float*)d_in[1];
    float* out     = (float*)d_out;

    const int nrows   = in_sizes[0] / 64;        // D = 64
    const long long n_threads = (long long)nrows * 16;
    const int block   = 256;
    const int grid    = (int)((n_threads + block - 1) / block);

    act_hyp_kernel<<<grid, block, 0, stream>>>(x, c, out, nrows);
}